// Round 10
// baseline (328.510 us; speedup 1.0000x reference)
//
#include <hip/hip_runtime.h>
#include <math.h>

// Problem constants (from reference)
#define N0_C  100000
#define N1_C  40000
#define N2_C  10000
#define E1_C  640000
#define E2_C  160000
#define D_IN_C  256
#define D_HID_C 256
#define D_OUT_C 128

// fixed-slot bucket width. Degrees are Poisson(16); P(deg>=64) ~ 3e-22 per
// node (1e-17 over all nodes). Overflow edges are dropped from the sum but
// counted in cnt — with this data no overflow occurs, result is exact.
#define MAXDEG 64

typedef __attribute__((ext_vector_type(8))) short short8;     // 8 bf16 (4 VGPRs)
typedef __attribute__((ext_vector_type(4))) float float4v;    // MFMA acc

// round-to-nearest-even fp32 -> bf16 bits
__device__ __forceinline__ unsigned short f2bf(float f) {
    unsigned int u = __float_as_uint(f);
    return (unsigned short)((u + 0x7FFFu + ((u >> 16) & 1u)) >> 16);
}
__device__ __forceinline__ float bf2f(unsigned int h) {
    return __uint_as_float(h << 16);
}

// async global->LDS, 16B per lane. LDS dest is wave-uniform base + lane*16
// (linear); global source is per-lane (rule #21: swizzle lives in the source
// layout + read addressing, never the LDS dest).
__device__ __forceinline__ void gload_lds16(const void* g, void* l) {
    __builtin_amdgcn_global_load_lds(
        (const __attribute__((address_space(1))) unsigned int*)g,
        (__attribute__((address_space(3))) unsigned int*)l, 16, 0, 0);
}

// ---------------------------------------------------------------------------
// prep: STREAMING ONLY (round-10: scatter de-overlapped again). R9 counters
// showed the conv<->scatter concurrency is mutually destructive: the stream
// evicts the scatter's perm2D/cnt L2 working set (WRITE amplification
// 36-49 MB) and the random RMWs wreck the stream's DRAM efficiency
// (2.1 TB/s vs ~5 standalone). conv + weight transposes + cnt zeroing
// (zeroing folded here so the separate hipMemsetAsync dispatch is deleted).
//
// Layer-1 weights are written in a CHUNK-MAJOR XOR-SWIZZLED layout so gemm1
// can stage them with linear global_load_lds and still read ds_read_b128
// bank-spread: within each 64-K block kt, logical (row r, chunk c of 8
// shorts) lives at entry slot (r*8 + (c ^ (r&7))), 16B per entry.
// Layer-2 weights keep the plain transposed layout (gemm2 unchanged).
// ---------------------------------------------------------------------------
#define PREP_CONV  6400000                       // N0*256/4 u64 items
#define PREP_TW    196608
#define PREP_TOTAL (PREP_CONV + PREP_TW + N1_C + N2_C)

__global__ void prep_kernel(const float* __restrict__ x,
                            const float* __restrict__ W1l,
                            const float* __restrict__ W1r,
                            const float* __restrict__ W2l,
                            const float* __restrict__ W2r,
                            unsigned short* __restrict__ xb,
                            unsigned short* __restrict__ wt1l,
                            unsigned short* __restrict__ wt1r,
                            unsigned short* __restrict__ wt2l,
                            unsigned short* __restrict__ wt2r,
                            int* __restrict__ cnt) {
    int stride = gridDim.x * blockDim.x;
    for (int id = blockIdx.x * blockDim.x + threadIdx.x; id < PREP_TOTAL; id += stride) {
        if (id < PREP_CONV) {
            float4 v = ((const float4*)x)[id];
            unsigned long long u = (unsigned long long)f2bf(v.x)
                                 | ((unsigned long long)f2bf(v.y) << 16)
                                 | ((unsigned long long)f2bf(v.z) << 32)
                                 | ((unsigned long long)f2bf(v.w) << 48);
            ((unsigned long long*)xb)[id] = u;
        } else if (id < PREP_CONV + PREP_TW) {
            int t = id - PREP_CONV;
            if (t < 131072) {
                // layer-1: chunk-major XOR layout, 256x256 each
                const float* W = (t < 65536) ? W1l : W1r;
                unsigned short* Wt = (t < 65536) ? wt1l : wt1r;
                int off = t & 65535;
                int k = off >> 8, n = off & 255;         // W[k][n], row-major
                int c  = (k >> 3) & 7;                   // chunk within 64-K block
                int cp = c ^ (n & 7);                    // swizzled slot
                int slot = (k >> 6) * 16384 + (n * 8 + cp) * 8 + (k & 7);
                Wt[slot] = f2bf(W[off]);
            } else {
                // layer-2: plain transposed layout Wt[n][k], 128x256 each
                int t2 = t - 131072;
                const float* W = (t2 < 32768) ? W2l : W2r;
                unsigned short* Wt = (t2 < 32768) ? wt2l : wt2r;
                int off = t2 & 32767;
                int k = off >> 7, n = off & 127;         // N=128
                Wt[n * 256 + k] = f2bf(W[off]);
            }
        } else {
            cnt[id - PREP_CONV - PREP_TW] = 0;           // cnt1+cnt2 contiguous
        }
    }
}

// ---------------------------------------------------------------------------
// scatter, ROUND-10: dst-partitioned XCD-affine (R9 structure) run STANDALONE
// so its working set stays L2-resident: cnt (200 KB) + per-XCD perm2D slice
// (1.6 MB at MAXDEG=64, NPART=8) fit in the 4 MB per-XCD L2 with no
// concurrent stream evicting them. Group g = blockIdx&7 processes only dsts
// in range g (exactly-once by membership test; a wrong %8->XCD mapping
// costs speed only, never correctness). Each group scans the full dst
// arrays (8x 3.2 MB, L3-hits after first pass).
// ---------------------------------------------------------------------------
#define PREP_E      (E1_C + E2_C)
#define SCAT_BLKS   1024
#define NPART       8
#define P1          (N1_C / NPART)               // 5000
#define P2          (N2_C / NPART)               // 1250

__global__ void scatter_part_kernel(const int* __restrict__ src1,
                                    const int* __restrict__ dst1,
                                    const int* __restrict__ src2,
                                    const int* __restrict__ dst2,
                                    int* __restrict__ cnt1, int* __restrict__ cnt2,
                                    int* __restrict__ perm2D1,
                                    int* __restrict__ perm2D2) {
    const int b   = blockIdx.x;
    const int g   = b & (NPART - 1);             // presumed XCD id
    const int bg  = b >> 3;                      // block within group, 0..127
    const int lo1 = g * P1, hi1 = lo1 + P1;
    const int lo2 = g * P2, hi2 = lo2 + P2;
    for (int e = bg * 256 + threadIdx.x; e < PREP_E;
         e += (SCAT_BLKS / NPART) * 256) {
        if (e < E1_C) {
            int d = min(max(dst1[e], 0), N1_C - 1);
            if (d >= lo1 && d < hi1) {
                int pos = atomicAdd(&cnt1[d], 1);
                if (pos < MAXDEG) perm2D1[d * MAXDEG + pos] = src1[e];
            }
        } else {
            int e2 = e - E1_C;
            int d = min(max(dst2[e2], 0), N2_C - 1);
            if (d >= lo2 && d < hi2) {
                int pos = atomicAdd(&cnt2[d], 1);
                if (pos < MAXDEG) perm2D2[d * MAXDEG + pos] = src2[e2];
            }
        }
    }
}

// ---------------------------------------------------------------------------
// gather-mean, bf16 in -> bf16 out. One wave per node; lanes 0-31 cover the
// 512B row of neighbor i, lanes 32-63 neighbor i+1 (16B/lane short8 loads).
// Round-3 A/B showed this is memory-system-bound; kept as the better variant.
// ---------------------------------------------------------------------------
__global__ __launch_bounds__(256)
void gather_mean_bf16_kernel(const unsigned short* __restrict__ feat,
                             const int* __restrict__ cnt,
                             const int* __restrict__ perm2D,
                             unsigned short* __restrict__ aggr,
                             int n, int nfeat) {
    int node = blockIdx.x * 4 + (threadIdx.x >> 6);
    int lane = threadIdx.x & 63;
    if (node >= n) return;
    const int half = lane >> 5;
    const int lc   = lane & 31;
    const int c_true = cnt[node];
    const int m = min(max(c_true, 0), MAXDEG);
    const int* __restrict__ row = perm2D + (size_t)node * MAXDEG;

    float a[8];
    #pragma unroll
    for (int j = 0; j < 8; ++j) a[j] = 0.f;

    int i = 0;
    for (; i + 8 <= m; i += 8) {
        int s0 = min(max(row[i     + half], 0), nfeat - 1);
        int s1 = min(max(row[i + 2 + half], 0), nfeat - 1);
        int s2 = min(max(row[i + 4 + half], 0), nfeat - 1);
        int s3 = min(max(row[i + 6 + half], 0), nfeat - 1);
        short8 v0 = *(const short8*)(feat + (size_t)s0 * 256 + lc * 8);
        short8 v1 = *(const short8*)(feat + (size_t)s1 * 256 + lc * 8);
        short8 v2 = *(const short8*)(feat + (size_t)s2 * 256 + lc * 8);
        short8 v3 = *(const short8*)(feat + (size_t)s3 * 256 + lc * 8);
        #pragma unroll
        for (int j = 0; j < 8; ++j)
            a[j] += (bf2f((unsigned int)(unsigned short)v0[j])
                   + bf2f((unsigned int)(unsigned short)v1[j]))
                  + (bf2f((unsigned int)(unsigned short)v2[j])
                   + bf2f((unsigned int)(unsigned short)v3[j]));
    }
    for (; i + 2 <= m; i += 2) {
        int s = min(max(row[i + half], 0), nfeat - 1);
        short8 v = *(const short8*)(feat + (size_t)s * 256 + lc * 8);
        #pragma unroll
        for (int j = 0; j < 8; ++j)
            a[j] += bf2f((unsigned int)(unsigned short)v[j]);
    }
    if (i < m && half == 0) {
        int s = min(max(row[i], 0), nfeat - 1);
        short8 v = *(const short8*)(feat + (size_t)s * 256 + lc * 8);
        #pragma unroll
        for (int j = 0; j < 8; ++j)
            a[j] += bf2f((unsigned int)(unsigned short)v[j]);
    }

    #pragma unroll
    for (int j = 0; j < 8; ++j) a[j] += __shfl_xor(a[j], 32, 64);

    if (half == 0) {
        float inv = (c_true > 0) ? 1.0f / (float)c_true : 0.0f;
        short8 o;
        #pragma unroll
        for (int j = 0; j < 8; ++j) o[j] = (short)f2bf(a[j] * inv);
        *(short8*)(aggr + (size_t)node * 256 + lc * 8) = o;
    }
}

// ---------------------------------------------------------------------------
// layer-1 MFMA GEMM: 64 rows x 256 cols per block (625 blocks = 2.4/CU;
// proven shape). Staging via global_load_lds width-16 (round-5/6, passed);
// bank-spread XOR baked into the global source layout and the ds_read
// addressing. LDS 40 KB. out_bf ALIASES A1 (h over xb in place).
// ---------------------------------------------------------------------------
__global__ __launch_bounds__(512)
void mfma_gemm1_kernel(const unsigned short* A0,
                       const unsigned short* A1,
                       const unsigned short* __restrict__ Wt0,   // swizzled layout
                       const unsigned short* __restrict__ Wt1,   // swizzled layout
                       const float* __restrict__ bias,
                       unsigned short* out_bf,
                       int M) {
    __shared__ unsigned short As[64 * 64];     // 8 KB   (entry e=(r*8+c'), 16B each)
    __shared__ unsigned short Bs[256 * 64];    // 32 KB

    const int tid  = threadIdx.x;
    const int lane = tid & 63;
    const int wid  = tid >> 6;         // 0..7
    const int wm   = wid & 1;
    const int wn   = wid >> 1;
    const int lr   = lane & 15;
    const int kq   = lane >> 4;
    const int row0 = blockIdx.x * 64;

    // A-stage mapping: wave wid stages entries [wid*64, wid*64+64):
    // lane -> r = wid*8 + (lane>>3), slot c' = lane&7 holding logical
    // chunk c = c' ^ (r&7) = (lane&7) ^ (lane>>3).
    const int a_r = wid * 8 + (lane >> 3);
    const int a_c = (lane & 7) ^ (lane >> 3);
    int a_row = row0 + a_r;
    if (a_row > M - 1) a_row = M - 1;

    float4v acc[2][4];
    #pragma unroll
    for (int a = 0; a < 2; ++a)
        #pragma unroll
        for (int b = 0; b < 4; ++b)
            #pragma unroll
            for (int c = 0; c < 4; ++c) acc[a][b][c] = 0.f;

    for (int p = 0; p < 2; ++p) {
        const unsigned short* A  = p ? A1  : A0;
        const unsigned short* __restrict__ Wt = p ? Wt1 : Wt0;
        for (int kt = 0; kt < 4; ++kt) {
            const int k0 = kt * 64;
            __syncthreads();                       // prev tile fully consumed
            // A tile: 64x64, 512 entries, 1 gload per wave
            gload_lds16(A + (size_t)a_row * 256 + k0 + a_c * 8, &As[wid * 512]);
            // B tile: 256x64, 2048 entries (contiguous in swizzled layout)
            #pragma unroll
            for (int i = 0; i < 4; ++i)
                gload_lds16(Wt + (size_t)kt * 16384 + ((wid * 4 + i) * 64 + lane) * 8,
                            &Bs[(wid * 4 + i) * 512]);
            __syncthreads();                       // vmcnt drained before barrier
            #pragma unroll
            for (int ks = 0; ks < 64; ks += 32) {
                const int ch = kq + (ks >> 3);     // logical chunk 0..7
                short8 af[2], bfr[4];
                #pragma unroll
                for (int t = 0; t < 2; ++t) {
                    int r = wm * 32 + t * 16 + lr;
                    af[t] = *(const short8*)&As[r * 64 + (ch ^ (lr & 7)) * 8];
                }
                #pragma unroll
                for (int t = 0; t < 4; ++t) {
                    int r = wn * 64 + t * 16 + lr;
                    bfr[t] = *(const short8*)&Bs[r * 64 + (ch ^ (lr & 7)) * 8];
                }
                #pragma unroll
                for (int ar = 0; ar < 2; ++ar)
                    #pragma unroll
                    for (int bc = 0; bc < 4; ++bc)
                        acc[ar][bc] = __builtin_amdgcn_mfma_f32_16x16x32_bf16(
                            af[ar], bfr[bc], acc[ar][bc], 0, 0, 0);
            }
        }
    }

    #pragma unroll
    for (int bc = 0; bc < 4; ++bc) {
        int col = wn * 64 + bc * 16 + lr;
        float bv = bias[col];
        #pragma unroll
        for (int ar = 0; ar < 2; ++ar) {
            int rowb = row0 + wm * 32 + ar * 16 + kq * 4;
            #pragma unroll
            for (int i = 0; i < 4; ++i) {
                int row = rowb + i;
                if (row < M)
                    out_bf[(size_t)row * 256 + col] = f2bf(fmaxf(acc[ar][bc][i] + bv, 0.f));
            }
        }
    }
}

// ---------------------------------------------------------------------------
// layer-2 MFMA GEMM (round-0 proven, unchanged; plain wt layout):
// out = sigmoid( A0@Wt0^T + A1@Wt1^T + b ), fp32 out.
// 64 rows x 128 cols per block, 256 threads (4 waves as 2x2).
// ---------------------------------------------------------------------------
__global__ __launch_bounds__(256)
void mfma_gemm2_kernel(const unsigned short* __restrict__ A0,
                       const unsigned short* __restrict__ A1,
                       const unsigned short* __restrict__ Wt0,
                       const unsigned short* __restrict__ Wt1,
                       const float* __restrict__ bias,
                       float* __restrict__ out_f,
                       int M, int N) {
    __shared__ unsigned short As[64][72];
    __shared__ unsigned short Bs[128][72];

    const int tid  = threadIdx.x;
    const int lane = tid & 63;
    const int wid  = tid >> 6;
    const int wm   = wid & 1;
    const int wn   = wid >> 1;
    const int lr   = lane & 15;
    const int kq   = lane >> 4;
    const int row0 = blockIdx.x * 64;

    float4v acc[2][4];
    #pragma unroll
    for (int a = 0; a < 2; ++a)
        #pragma unroll
        for (int b = 0; b < 4; ++b)
            #pragma unroll
            for (int c = 0; c < 4; ++c) acc[a][b][c] = 0.f;

    for (int p = 0; p < 2; ++p) {
        const unsigned short* __restrict__ A  = p ? A1  : A0;
        const unsigned short* __restrict__ Wt = p ? Wt1 : Wt0;
        for (int kt = 0; kt < 4; ++kt) {
            const int k0 = kt * 64;
            __syncthreads();
            #pragma unroll
            for (int i = 0; i < 2; ++i) {
                int idx = tid + i * 256;
                int r = idx >> 3, sc = (idx & 7) * 8;
                int row = row0 + r;
                if (row > M - 1) row = M - 1;
                *(short8*)&As[r][sc] = *(const short8*)(A + (size_t)row * 256 + k0 + sc);
            }
            #pragma unroll
            for (int i = 0; i < 4; ++i) {
                int idx = tid + i * 256;
                int r = idx >> 3, sc = (idx & 7) * 8;
                *(short8*)&Bs[r][sc] = *(const short8*)(Wt + (size_t)r * 256 + k0 + sc);
            }
            __syncthreads();
            #pragma unroll
            for (int ks = 0; ks < 64; ks += 32) {
                short8 af[2], bfr[4];
                #pragma unroll
                for (int t = 0; t < 2; ++t)
                    af[t]  = *(const short8*)&As[wm * 32 + t * 16 + lr][ks + kq * 8];
                #pragma unroll
                for (int t = 0; t < 4; ++t)
                    bfr[t] = *(const short8*)&Bs[wn * 64 + t * 16 + lr][ks + kq * 8];
                #pragma unroll
                for (int ar = 0; ar < 2; ++ar)
                    #pragma unroll
                    for (int bc = 0; bc < 4; ++bc)
                        acc[ar][bc] = __builtin_amdgcn_mfma_f32_16x16x32_bf16(
                            af[ar], bfr[bc], acc[ar][bc], 0, 0, 0);
            }
        }
    }

    #pragma unroll
    for (int bc = 0; bc < 4; ++bc) {
        int col = wn * 64 + bc * 16 + lr;
        float bv = bias[col];
        #pragma unroll
        for (int ar = 0; ar < 2; ++ar) {
            int rowb = row0 + wm * 32 + ar * 16 + kq * 4;
            #pragma unroll
            for (int i = 0; i < 4; ++i) {
                int row = rowb + i;
                if (row < M)
                    out_f[(size_t)row * N + col] =
                        1.0f / (1.0f + __expf(-(acc[ar][bc][i] + bv)));
            }
        }
    }
}

// ---------------------------------------------------------------------------
// launch (6 kernel dispatches, no memset — cnt zeroing folded into prep)
// ---------------------------------------------------------------------------
extern "C" void kernel_launch(void* const* d_in, const int* in_sizes, int n_in,
                              void* d_out, int out_size, void* d_ws, size_t ws_size,
                              hipStream_t stream) {
    const float* x   = (const float*)d_in[0];
    const float* W1l = (const float*)d_in[1];
    const float* b1  = (const float*)d_in[2];
    const float* W1r = (const float*)d_in[3];
    const float* W2l = (const float*)d_in[4];
    const float* b2  = (const float*)d_in[5];
    const float* W2r = (const float*)d_in[6];
    const int* src1  = (const int*)d_in[7];
    const int* dst1  = (const int*)d_in[8];
    const int* src2  = (const int*)d_in[9];
    const int* dst2  = (const int*)d_in[10];
    float* out = (float*)d_out;

    // workspace layout (~85 MB; h aliases xb in place, aggr2 aliases aggr1)
    unsigned short* us = (unsigned short*)d_ws;
    unsigned short* xb    = us;                          us += (size_t)N0_C * 256;
    unsigned short* h     = xb;                          // alias (in-place gemm1)
    unsigned short* aggr1 = us;                          us += (size_t)N1_C * 256;
    unsigned short* aggr2 = aggr1;                       // alias (aggr1 dead after gemm1)
    unsigned short* wt1l  = us;                          us += 256 * 256;
    unsigned short* wt1r  = us;                          us += 256 * 256;
    unsigned short* wt2l  = us;                          us += 128 * 256;
    unsigned short* wt2r  = us;                          us += 128 * 256;
    int* ip = (int*)us;
    int* cnt1    = ip;                 ip += N1_C;       // cnt1+cnt2 contiguous
    int* cnt2    = ip;                 ip += N2_C;
    int* perm2D1 = ip;                 ip += (size_t)N1_C * MAXDEG;
    int* perm2D2 = ip;                 ip += (size_t)N2_C * MAXDEG;

    // ---- 1: streaming precompute (x->bf16, weight transposes, cnt zero) ----
    prep_kernel<<<2048, 256, 0, stream>>>(x, W1l, W1r, W2l, W2r,
                                          xb, wt1l, wt1r, wt2l, wt2r, cnt1);

    // ---- 2: dst-partitioned scatter, standalone (L2-resident working set) ----
    scatter_part_kernel<<<SCAT_BLKS, 256, 0, stream>>>(
        src1, dst1, src2, dst2, cnt1, cnt2, perm2D1, perm2D2);

    // ---- 3: layer-1 gather-mean ----
    gather_mean_bf16_kernel<<<(N1_C + 3) / 4, 256, 0, stream>>>(xb, cnt1, perm2D1,
                                                                aggr1, N1_C, N0_C);
    // ---- 4: layer-1 GEMM (64x256 tile, global_load_lds staging) ----
    mfma_gemm1_kernel<<<(N1_C + 63) / 64, 512, 0, stream>>>(aggr1, xb, wt1l, wt1r,
                                                            b1, h, N1_C);

    // ---- 5: layer-2 gather-mean ----
    gather_mean_bf16_kernel<<<(N2_C + 3) / 4, 256, 0, stream>>>(h, cnt2, perm2D2,
                                                                aggr2, N2_C, N1_C);
    // ---- 6: layer-2 GEMM -> fp32 out ----
    mfma_gemm2_kernel<<<(N2_C + 63) / 64, 256, 0, stream>>>(aggr2, h, wt2l, wt2r,
                                                            b2, out, N2_C, D_OUT_C);
}

// Round 11
// 304.131 us; speedup vs baseline: 1.0802x; 1.0802x over previous
//
#include <hip/hip_runtime.h>
#include <math.h>

// Problem constants (from reference)
#define N0_C  100000
#define N1_C  40000
#define N2_C  10000
#define E1_C  640000
#define E2_C  160000
#define D_IN_C  256
#define D_HID_C 256
#define D_OUT_C 128

// fixed-slot bucket width. Degrees are Poisson(16); P(deg>=64) ~ 3e-22 per
// node (1e-17 over all nodes). Overflow edges are dropped from the sum but
// counted in cnt — with this data no overflow occurs, result is exact.
#define MAXDEG 64

typedef __attribute__((ext_vector_type(8))) short short8;     // 8 bf16 (4 VGPRs)
typedef __attribute__((ext_vector_type(4))) float float4v;    // MFMA acc

// round-to-nearest-even fp32 -> bf16 bits
__device__ __forceinline__ unsigned short f2bf(float f) {
    unsigned int u = __float_as_uint(f);
    return (unsigned short)((u + 0x7FFFu + ((u >> 16) & 1u)) >> 16);
}
__device__ __forceinline__ float bf2f(unsigned int h) {
    return __uint_as_float(h << 16);
}

// async global->LDS, 16B per lane. LDS dest is wave-uniform base + lane*16
// (linear); global source is per-lane (rule #21: swizzle lives in the source
// layout + read addressing, never the LDS dest).
__device__ __forceinline__ void gload_lds16(const void* g, void* l) {
    __builtin_amdgcn_global_load_lds(
        (const __attribute__((address_space(1))) unsigned int*)g,
        (__attribute__((address_space(3))) unsigned int*)l, 16, 0, 0);
}

// ---------------------------------------------------------------------------
// prep_scatter: BLOCK-RANGE-SPLIT concurrency — the round-8 measured-best
// configuration, restored verbatim. Session evidence:
//   R7/R8: overlap nets -20us vs serial despite stream<->scatter L2
//          interference (R10 de-overlap regressed +21us).
//   R8:    scatter TLP 512->960 blocks: null -> not latency-bound.
//   R9:    dst-partitioned XCD-affine scatter: null -> not line-ping-pong.
//   R10:   partitioned standalone: ~= R6 standalone -> ~35-40us scatter cost
//          is intrinsic to the 800K atomic+dependent-random-store chains.
// Block layout (2048 total = 8/CU, all co-resident):
//   [0,1024):    x->bf16 conversion (streaming, BW-bound)
//   [1024,1088): weight transposes
//   [1088,2048): edge scatter (960 blocks, 3.3 edges/thread)
// cnt zeroed by hipMemsetAsync beforehand.
//
// Layer-1 weights are written in a CHUNK-MAJOR XOR-SWIZZLED layout so gemm1
// can stage them with linear global_load_lds and still read ds_read_b128
// bank-spread: within each 64-K block kt, logical (row r, chunk c of 8
// shorts) lives at entry slot (r*8 + (c ^ (r&7))), 16B per entry.
// Layer-2 weights keep the plain transposed layout (gemm2 unchanged).
// ---------------------------------------------------------------------------
#define PREP_CONV   6400000                      // N0*256/4 u64 items
#define PREP_TW     196608
#define PREP_E      (E1_C + E2_C)
#define CONV_BLKS   1024
#define TW_BLKS     64
#define SCAT_BLKS   960
#define TOTAL_BLKS  (CONV_BLKS + TW_BLKS + SCAT_BLKS)   // 2048

__global__ void prep_scatter_kernel(const float* __restrict__ x,
                                    const float* __restrict__ W1l,
                                    const float* __restrict__ W1r,
                                    const float* __restrict__ W2l,
                                    const float* __restrict__ W2r,
                                    const int* __restrict__ src1,
                                    const int* __restrict__ dst1,
                                    const int* __restrict__ src2,
                                    const int* __restrict__ dst2,
                                    unsigned short* __restrict__ xb,
                                    unsigned short* __restrict__ wt1l,
                                    unsigned short* __restrict__ wt1r,
                                    unsigned short* __restrict__ wt2l,
                                    unsigned short* __restrict__ wt2r,
                                    int* __restrict__ cnt1, int* __restrict__ cnt2,
                                    int* __restrict__ perm2D1,
                                    int* __restrict__ perm2D2) {
    const int b = blockIdx.x;
    if (b < CONV_BLKS) {
        // ---- streaming conversion: float4 load -> packed u64 bf16 store ----
        for (int id = b * 256 + threadIdx.x; id < PREP_CONV; id += CONV_BLKS * 256) {
            float4 v = ((const float4*)x)[id];
            unsigned long long u = (unsigned long long)f2bf(v.x)
                                 | ((unsigned long long)f2bf(v.y) << 16)
                                 | ((unsigned long long)f2bf(v.z) << 32)
                                 | ((unsigned long long)f2bf(v.w) << 48);
            ((unsigned long long*)xb)[id] = u;
        }
    } else if (b < CONV_BLKS + TW_BLKS) {
        // ---- weight transposes ----
        for (int t = (b - CONV_BLKS) * 256 + threadIdx.x; t < PREP_TW; t += TW_BLKS * 256) {
            if (t < 131072) {
                // layer-1: chunk-major XOR layout, 256x256 each
                const float* W = (t < 65536) ? W1l : W1r;
                unsigned short* Wt = (t < 65536) ? wt1l : wt1r;
                int off = t & 65535;
                int k = off >> 8, n = off & 255;         // W[k][n], row-major
                int c  = (k >> 3) & 7;                   // chunk within 64-K block
                int cp = c ^ (n & 7);                    // swizzled slot
                int slot = (k >> 6) * 16384 + (n * 8 + cp) * 8 + (k & 7);
                Wt[slot] = f2bf(W[off]);
            } else {
                // layer-2: plain transposed layout Wt[n][k], 128x256 each
                int t2 = t - 131072;
                const float* W = (t2 < 32768) ? W2l : W2r;
                unsigned short* Wt = (t2 < 32768) ? wt2l : wt2r;
                int off = t2 & 32767;
                int k = off >> 7, n = off & 127;         // N=128
                Wt[n * 256 + k] = f2bf(W[off]);
            }
        }
    } else {
        // ---- edge scatter: pos = cnt[d]++, perm2D[d][pos] = src ----
        for (int e = (b - CONV_BLKS - TW_BLKS) * 256 + threadIdx.x; e < PREP_E;
             e += SCAT_BLKS * 256) {
            if (e < E1_C) {
                int d = min(max(dst1[e], 0), N1_C - 1);
                int pos = atomicAdd(&cnt1[d], 1);
                if (pos < MAXDEG) perm2D1[d * MAXDEG + pos] = src1[e];
            } else {
                int e2 = e - E1_C;
                int d = min(max(dst2[e2], 0), N2_C - 1);
                int pos = atomicAdd(&cnt2[d], 1);
                if (pos < MAXDEG) perm2D2[d * MAXDEG + pos] = src2[e2];
            }
        }
    }
}

// ---------------------------------------------------------------------------
// gather-mean, bf16 in -> bf16 out. One wave per node; lanes 0-31 cover the
// 512B row of neighbor i, lanes 32-63 neighbor i+1 (16B/lane short8 loads).
// Round-3 A/B showed this is memory-system-bound; kept as the better variant.
// ---------------------------------------------------------------------------
__global__ __launch_bounds__(256)
void gather_mean_bf16_kernel(const unsigned short* __restrict__ feat,
                             const int* __restrict__ cnt,
                             const int* __restrict__ perm2D,
                             unsigned short* __restrict__ aggr,
                             int n, int nfeat) {
    int node = blockIdx.x * 4 + (threadIdx.x >> 6);
    int lane = threadIdx.x & 63;
    if (node >= n) return;
    const int half = lane >> 5;
    const int lc   = lane & 31;
    const int c_true = cnt[node];
    const int m = min(max(c_true, 0), MAXDEG);
    const int* __restrict__ row = perm2D + (size_t)node * MAXDEG;

    float a[8];
    #pragma unroll
    for (int j = 0; j < 8; ++j) a[j] = 0.f;

    int i = 0;
    for (; i + 8 <= m; i += 8) {
        int s0 = min(max(row[i     + half], 0), nfeat - 1);
        int s1 = min(max(row[i + 2 + half], 0), nfeat - 1);
        int s2 = min(max(row[i + 4 + half], 0), nfeat - 1);
        int s3 = min(max(row[i + 6 + half], 0), nfeat - 1);
        short8 v0 = *(const short8*)(feat + (size_t)s0 * 256 + lc * 8);
        short8 v1 = *(const short8*)(feat + (size_t)s1 * 256 + lc * 8);
        short8 v2 = *(const short8*)(feat + (size_t)s2 * 256 + lc * 8);
        short8 v3 = *(const short8*)(feat + (size_t)s3 * 256 + lc * 8);
        #pragma unroll
        for (int j = 0; j < 8; ++j)
            a[j] += (bf2f((unsigned int)(unsigned short)v0[j])
                   + bf2f((unsigned int)(unsigned short)v1[j]))
                  + (bf2f((unsigned int)(unsigned short)v2[j])
                   + bf2f((unsigned int)(unsigned short)v3[j]));
    }
    for (; i + 2 <= m; i += 2) {
        int s = min(max(row[i + half], 0), nfeat - 1);
        short8 v = *(const short8*)(feat + (size_t)s * 256 + lc * 8);
        #pragma unroll
        for (int j = 0; j < 8; ++j)
            a[j] += bf2f((unsigned int)(unsigned short)v[j]);
    }
    if (i < m && half == 0) {
        int s = min(max(row[i], 0), nfeat - 1);
        short8 v = *(const short8*)(feat + (size_t)s * 256 + lc * 8);
        #pragma unroll
        for (int j = 0; j < 8; ++j)
            a[j] += bf2f((unsigned int)(unsigned short)v[j]);
    }

    #pragma unroll
    for (int j = 0; j < 8; ++j) a[j] += __shfl_xor(a[j], 32, 64);

    if (half == 0) {
        float inv = (c_true > 0) ? 1.0f / (float)c_true : 0.0f;
        short8 o;
        #pragma unroll
        for (int j = 0; j < 8; ++j) o[j] = (short)f2bf(a[j] * inv);
        *(short8*)(aggr + (size_t)node * 256 + lc * 8) = o;
    }
}

// ---------------------------------------------------------------------------
// layer-1 MFMA GEMM: 64 rows x 256 cols per block (625 blocks = 2.4/CU;
// proven shape). Staging via global_load_lds width-16 (round-5/6, passed);
// bank-spread XOR baked into the global source layout and the ds_read
// addressing. LDS 40 KB. out_bf ALIASES A1 (h over xb in place).
// ---------------------------------------------------------------------------
__global__ __launch_bounds__(512)
void mfma_gemm1_kernel(const unsigned short* A0,
                       const unsigned short* A1,
                       const unsigned short* __restrict__ Wt0,   // swizzled layout
                       const unsigned short* __restrict__ Wt1,   // swizzled layout
                       const float* __restrict__ bias,
                       unsigned short* out_bf,
                       int M) {
    __shared__ unsigned short As[64 * 64];     // 8 KB   (entry e=(r*8+c'), 16B each)
    __shared__ unsigned short Bs[256 * 64];    // 32 KB

    const int tid  = threadIdx.x;
    const int lane = tid & 63;
    const int wid  = tid >> 6;         // 0..7
    const int wm   = wid & 1;
    const int wn   = wid >> 1;
    const int lr   = lane & 15;
    const int kq   = lane >> 4;
    const int row0 = blockIdx.x * 64;

    // A-stage mapping: wave wid stages entries [wid*64, wid*64+64):
    // lane -> r = wid*8 + (lane>>3), slot c' = lane&7 holding logical
    // chunk c = c' ^ (r&7) = (lane&7) ^ (lane>>3).
    const int a_r = wid * 8 + (lane >> 3);
    const int a_c = (lane & 7) ^ (lane >> 3);
    int a_row = row0 + a_r;
    if (a_row > M - 1) a_row = M - 1;

    float4v acc[2][4];
    #pragma unroll
    for (int a = 0; a < 2; ++a)
        #pragma unroll
        for (int b = 0; b < 4; ++b)
            #pragma unroll
            for (int c = 0; c < 4; ++c) acc[a][b][c] = 0.f;

    for (int p = 0; p < 2; ++p) {
        const unsigned short* A  = p ? A1  : A0;
        const unsigned short* __restrict__ Wt = p ? Wt1 : Wt0;
        for (int kt = 0; kt < 4; ++kt) {
            const int k0 = kt * 64;
            __syncthreads();                       // prev tile fully consumed
            // A tile: 64x64, 512 entries, 1 gload per wave
            gload_lds16(A + (size_t)a_row * 256 + k0 + a_c * 8, &As[wid * 512]);
            // B tile: 256x64, 2048 entries (contiguous in swizzled layout)
            #pragma unroll
            for (int i = 0; i < 4; ++i)
                gload_lds16(Wt + (size_t)kt * 16384 + ((wid * 4 + i) * 64 + lane) * 8,
                            &Bs[(wid * 4 + i) * 512]);
            __syncthreads();                       // vmcnt drained before barrier
            #pragma unroll
            for (int ks = 0; ks < 64; ks += 32) {
                const int ch = kq + (ks >> 3);     // logical chunk 0..7
                short8 af[2], bfr[4];
                #pragma unroll
                for (int t = 0; t < 2; ++t) {
                    int r = wm * 32 + t * 16 + lr;
                    af[t] = *(const short8*)&As[r * 64 + (ch ^ (lr & 7)) * 8];
                }
                #pragma unroll
                for (int t = 0; t < 4; ++t) {
                    int r = wn * 64 + t * 16 + lr;
                    bfr[t] = *(const short8*)&Bs[r * 64 + (ch ^ (lr & 7)) * 8];
                }
                #pragma unroll
                for (int ar = 0; ar < 2; ++ar)
                    #pragma unroll
                    for (int bc = 0; bc < 4; ++bc)
                        acc[ar][bc] = __builtin_amdgcn_mfma_f32_16x16x32_bf16(
                            af[ar], bfr[bc], acc[ar][bc], 0, 0, 0);
            }
        }
    }

    #pragma unroll
    for (int bc = 0; bc < 4; ++bc) {
        int col = wn * 64 + bc * 16 + lr;
        float bv = bias[col];
        #pragma unroll
        for (int ar = 0; ar < 2; ++ar) {
            int rowb = row0 + wm * 32 + ar * 16 + kq * 4;
            #pragma unroll
            for (int i = 0; i < 4; ++i) {
                int row = rowb + i;
                if (row < M)
                    out_bf[(size_t)row * 256 + col] = f2bf(fmaxf(acc[ar][bc][i] + bv, 0.f));
            }
        }
    }
}

// ---------------------------------------------------------------------------
// layer-2 MFMA GEMM (round-0 proven, unchanged; plain wt layout):
// out = sigmoid( A0@Wt0^T + A1@Wt1^T + b ), fp32 out.
// 64 rows x 128 cols per block, 256 threads (4 waves as 2x2).
// ---------------------------------------------------------------------------
__global__ __launch_bounds__(256)
void mfma_gemm2_kernel(const unsigned short* __restrict__ A0,
                       const unsigned short* __restrict__ A1,
                       const unsigned short* __restrict__ Wt0,
                       const unsigned short* __restrict__ Wt1,
                       const float* __restrict__ bias,
                       float* __restrict__ out_f,
                       int M, int N) {
    __shared__ unsigned short As[64][72];
    __shared__ unsigned short Bs[128][72];

    const int tid  = threadIdx.x;
    const int lane = tid & 63;
    const int wid  = tid >> 6;
    const int wm   = wid & 1;
    const int wn   = wid >> 1;
    const int lr   = lane & 15;
    const int kq   = lane >> 4;
    const int row0 = blockIdx.x * 64;

    float4v acc[2][4];
    #pragma unroll
    for (int a = 0; a < 2; ++a)
        #pragma unroll
        for (int b = 0; b < 4; ++b)
            #pragma unroll
            for (int c = 0; c < 4; ++c) acc[a][b][c] = 0.f;

    for (int p = 0; p < 2; ++p) {
        const unsigned short* __restrict__ A  = p ? A1  : A0;
        const unsigned short* __restrict__ Wt = p ? Wt1 : Wt0;
        for (int kt = 0; kt < 4; ++kt) {
            const int k0 = kt * 64;
            __syncthreads();
            #pragma unroll
            for (int i = 0; i < 2; ++i) {
                int idx = tid + i * 256;
                int r = idx >> 3, sc = (idx & 7) * 8;
                int row = row0 + r;
                if (row > M - 1) row = M - 1;
                *(short8*)&As[r][sc] = *(const short8*)(A + (size_t)row * 256 + k0 + sc);
            }
            #pragma unroll
            for (int i = 0; i < 4; ++i) {
                int idx = tid + i * 256;
                int r = idx >> 3, sc = (idx & 7) * 8;
                *(short8*)&Bs[r][sc] = *(const short8*)(Wt + (size_t)r * 256 + k0 + sc);
            }
            __syncthreads();
            #pragma unroll
            for (int ks = 0; ks < 64; ks += 32) {
                short8 af[2], bfr[4];
                #pragma unroll
                for (int t = 0; t < 2; ++t)
                    af[t]  = *(const short8*)&As[wm * 32 + t * 16 + lr][ks + kq * 8];
                #pragma unroll
                for (int t = 0; t < 4; ++t)
                    bfr[t] = *(const short8*)&Bs[wn * 64 + t * 16 + lr][ks + kq * 8];
                #pragma unroll
                for (int ar = 0; ar < 2; ++ar)
                    #pragma unroll
                    for (int bc = 0; bc < 4; ++bc)
                        acc[ar][bc] = __builtin_amdgcn_mfma_f32_16x16x32_bf16(
                            af[ar], bfr[bc], acc[ar][bc], 0, 0, 0);
            }
        }
    }

    #pragma unroll
    for (int bc = 0; bc < 4; ++bc) {
        int col = wn * 64 + bc * 16 + lr;
        float bv = bias[col];
        #pragma unroll
        for (int ar = 0; ar < 2; ++ar) {
            int rowb = row0 + wm * 32 + ar * 16 + kq * 4;
            #pragma unroll
            for (int i = 0; i < 4; ++i) {
                int row = rowb + i;
                if (row < M)
                    out_f[(size_t)row * N + col] =
                        1.0f / (1.0f + __expf(-(acc[ar][bc][i] + bv)));
            }
        }
    }
}

// ---------------------------------------------------------------------------
// launch (1 memset + 5 kernel dispatches) — round-8 measured-best config
// ---------------------------------------------------------------------------
extern "C" void kernel_launch(void* const* d_in, const int* in_sizes, int n_in,
                              void* d_out, int out_size, void* d_ws, size_t ws_size,
                              hipStream_t stream) {
    const float* x   = (const float*)d_in[0];
    const float* W1l = (const float*)d_in[1];
    const float* b1  = (const float*)d_in[2];
    const float* W1r = (const float*)d_in[3];
    const float* W2l = (const float*)d_in[4];
    const float* b2  = (const float*)d_in[5];
    const float* W2r = (const float*)d_in[6];
    const int* src1  = (const int*)d_in[7];
    const int* dst1  = (const int*)d_in[8];
    const int* src2  = (const int*)d_in[9];
    const int* dst2  = (const int*)d_in[10];
    float* out = (float*)d_out;

    // workspace layout (~85 MB; h aliases xb in place, aggr2 aliases aggr1)
    unsigned short* us = (unsigned short*)d_ws;
    unsigned short* xb    = us;                          us += (size_t)N0_C * 256;
    unsigned short* h     = xb;                          // alias (in-place gemm1)
    unsigned short* aggr1 = us;                          us += (size_t)N1_C * 256;
    unsigned short* aggr2 = aggr1;                       // alias (aggr1 dead after gemm1)
    unsigned short* wt1l  = us;                          us += 256 * 256;
    unsigned short* wt1r  = us;                          us += 256 * 256;
    unsigned short* wt2l  = us;                          us += 128 * 256;
    unsigned short* wt2r  = us;                          us += 128 * 256;
    int* ip = (int*)us;
    int* cnt1    = ip;                 ip += N1_C;       // cnt1+cnt2 contiguous
    int* cnt2    = ip;                 ip += N2_C;
    int* perm2D1 = ip;                 ip += (size_t)N1_C * MAXDEG;
    int* perm2D2 = ip;                 ip += (size_t)N2_C * MAXDEG;

    // ---- 0: zero the degree counters ----
    hipMemsetAsync(cnt1, 0, (size_t)(N1_C + N2_C) * sizeof(int), stream);

    // ---- 1: concurrent precompute + scatter (block-range split, R8 split) ----
    prep_scatter_kernel<<<TOTAL_BLKS, 256, 0, stream>>>(
        x, W1l, W1r, W2l, W2r, src1, dst1, src2, dst2,
        xb, wt1l, wt1r, wt2l, wt2r, cnt1, cnt2, perm2D1, perm2D2);

    // ---- 2: layer-1 gather-mean ----
    gather_mean_bf16_kernel<<<(N1_C + 3) / 4, 256, 0, stream>>>(xb, cnt1, perm2D1,
                                                                aggr1, N1_C, N0_C);
    // ---- 3: layer-1 GEMM (64x256 tile, global_load_lds staging) ----
    mfma_gemm1_kernel<<<(N1_C + 63) / 64, 512, 0, stream>>>(aggr1, xb, wt1l, wt1r,
                                                            b1, h, N1_C);

    // ---- 4: layer-2 gather-mean ----
    gather_mean_bf16_kernel<<<(N2_C + 3) / 4, 256, 0, stream>>>(h, cnt2, perm2D2,
                                                                aggr2, N2_C, N1_C);
    // ---- 5: layer-2 GEMM -> fp32 out ----
    mfma_gemm2_kernel<<<(N2_C + 63) / 64, 256, 0, stream>>>(aggr2, h, wt2l, wt2r,
                                                            b2, out, N2_C, D_OUT_C);
}